// Round 1
// baseline (4473.076 us; speedup 1.0000x reference)
//
#include <hip/hip_runtime.h>
#include <math.h>

typedef __bf16 bf16x8 __attribute__((ext_vector_type(8)));
typedef float floatx4 __attribute__((ext_vector_type(4)));

#define Tc 2048
#define Cdim 1024
#define Hc 16
#define Dc 64
#define Mrows 8192

__device__ __forceinline__ float bf2f(ushort u) {
  union { float f; unsigned int i; } v; v.i = ((unsigned int)u) << 16; return v.f;
}
__device__ __forceinline__ ushort f2bf(float f) {
  union { float f; unsigned int i; } v; v.f = f;
  unsigned int r = (v.i + 0x7FFFu + ((v.i >> 16) & 1u)) >> 16;
  return (ushort)r;
}
__device__ __forceinline__ float wmax(float v) {
  #pragma unroll
  for (int o = 32; o > 0; o >>= 1) v = fmaxf(v, __shfl_xor(v, o));
  return v;
}
__device__ __forceinline__ float wsum(float v) {
  #pragma unroll
  for (int o = 32; o > 0; o >>= 1) v += __shfl_xor(v, o);
  return v;
}

// ---------- dtype sniff: 1 = bf16-packed input, 0 = fp32 input ----------
__global__ void sniff_kernel(const unsigned int* __restrict__ x, int* __restrict__ flag) {
  __shared__ int cnt;
  if (threadIdx.x == 0) cnt = 0;
  __syncthreads();
  int local = 0;
  for (int i = threadIdx.x; i < 1024; i += 256) {
    unsigned int w = x[i];
    unsigned int e = (w >> 7) & 0xFFu;  // exponent field of LOW bf16 half
    if (e >= 100u && e <= 140u) local++;
  }
  atomicAdd(&cnt, local);
  __syncthreads();
  if (threadIdx.x == 0) *flag = (cnt >= 614) ? 1 : 0;
}

// ---------- convert (copy) to canonical bf16 bits ----------
__global__ void convert_vec(const void* __restrict__ src, ushort* __restrict__ dst,
                            size_t n, const int* __restrict__ flag) {
  size_t i = (size_t)blockIdx.x * blockDim.x + threadIdx.x;
  size_t base = i * 4;
  if (base >= n) return;
  if (*flag) {
    *(ushort4*)(dst + base) = ((const ushort4*)src)[i];
  } else {
    float4 f = ((const float4*)src)[i];
    dst[base + 0] = f2bf(f.x);
    dst[base + 1] = f2bf(f.y);
    dst[base + 2] = f2bf(f.z);
    dst[base + 3] = f2bf(f.w);
  }
}

// ---------- transpose + convert: src[R][Ccols] -> dst[Ccols][R] (bf16) ----------
__global__ void transpose_convert(const void* __restrict__ src, ushort* __restrict__ dst,
                                  int R, int Ccols, const int* __restrict__ flag) {
  __shared__ float tile[32][33];
  const int bx = blockIdx.x, by = blockIdx.y;
  const int tx = threadIdx.x, ty = threadIdx.y;
  const bool isbf = (*flag != 0);
  #pragma unroll
  for (int i = ty; i < 32; i += 8) {
    int r = by * 32 + i;
    int c = bx * 32 + tx;
    float v = isbf ? bf2f(((const ushort*)src)[(size_t)r * Ccols + c])
                   : ((const float*)src)[(size_t)r * Ccols + c];
    tile[i][tx] = v;
  }
  __syncthreads();
  #pragma unroll
  for (int i = ty; i < 32; i += 8) {
    int cc = bx * 32 + i;       // new row (old col)
    int rr = by * 32 + tx;      // new col (old row)
    dst[(size_t)cc * R + rr] = f2bf(tile[tx][i]);
  }
}

// ---------- GEMM 1: qkv = x @ W_qkv + b, scatter into Q / K^T / V ----------
// A[M,K] bf16, Bt[N,K] bf16. 64x64 tile, BK=32, 4 waves, mfma 16x16x32.
__global__ __launch_bounds__(256) void gemm_qkv(const ushort* __restrict__ A,
                                                const ushort* __restrict__ Bt,
                                                const ushort* __restrict__ bias,
                                                ushort* __restrict__ Qb,
                                                ushort* __restrict__ Ktb,
                                                ushort* __restrict__ Vb) {
  constexpr int K = 1024;
  __shared__ __align__(16) ushort As[64 * 40];
  __shared__ __align__(16) ushort Bs[64 * 40];
  const int tid = threadIdx.x;
  const int wave = tid >> 6, lane = tid & 63;
  const int m0 = blockIdx.y * 64;
  const int n0 = blockIdx.x * 64;
  const int srow = tid >> 2;          // 0..63
  const int scol = (tid & 3) * 8;     // 0,8,16,24
  const size_t a_src = (size_t)(m0 + srow) * K + scol;
  const size_t b_src = (size_t)(n0 + srow) * K + scol;
  const int lds_dst = srow * 40 + scol;
  const int mr = lane & 15, quad = lane >> 4;
  const int a_off = (wave * 16 + mr) * 40 + quad * 8;
  floatx4 acc[4] = {{0.f,0.f,0.f,0.f},{0.f,0.f,0.f,0.f},{0.f,0.f,0.f,0.f},{0.f,0.f,0.f,0.f}};
  for (int k0 = 0; k0 < K; k0 += 32) {
    uint4 av = *(const uint4*)(A + a_src + k0);
    uint4 bv = *(const uint4*)(Bt + b_src + k0);
    __syncthreads();
    *(uint4*)(As + lds_dst) = av;
    *(uint4*)(Bs + lds_dst) = bv;
    __syncthreads();
    bf16x8 af = *(const bf16x8*)(As + a_off);
    #pragma unroll
    for (int c = 0; c < 4; ++c) {
      bf16x8 bf = *(const bf16x8*)(Bs + (c * 16 + mr) * 40 + quad * 8);
      acc[c] = __builtin_amdgcn_mfma_f32_16x16x32_bf16(af, bf, acc[c], 0, 0, 0);
    }
  }
  // epilogue: D mapping col=lane&15 (within 16-tile), row=quad*4+reg
  #pragma unroll
  for (int c = 0; c < 4; ++c) {
    const int col = n0 + c * 16 + mr;        // 0..3071
    const float bi = bf2f(bias[col]);
    const int which = col >> 10;             // 0=Q 1=K 2=V
    const int within = col & 1023;
    const int h = within >> 6, d = within & 63;
    #pragma unroll
    for (int r = 0; r < 4; ++r) {
      const int row = m0 + wave * 16 + quad * 4 + r;   // 0..8191
      const float v = acc[c][r] + bi;
      const int b = row >> 11, t = row & 2047;
      const size_t hb = (size_t)(b * Hc + h);
      const ushort ub = f2bf(v);
      if (which == 0)      Qb[(hb * Tc + t) * Dc + d] = ub;
      else if (which == 1) Ktb[(hb * Dc + d) * Tc + t] = ub;
      else                 Vb[(hb * Tc + t) * Dc + d] = ub;
    }
  }
}

// ---------- flash attention (VALU, correctness-first) ----------
// grid: (T/16, B*H). 4 waves/block, 4 q-rows per wave. lane = d for Q/O, lane = kpos for S/P.
__global__ __launch_bounds__(256) void attn_kernel(const ushort* __restrict__ Qb,
                                                   const ushort* __restrict__ Ktb,
                                                   const ushort* __restrict__ Vb,
                                                   ushort* __restrict__ Yb) {
  const int bh = blockIdx.y;
  const int wave = threadIdx.x >> 6, lane = threadIdx.x & 63;
  const int r0 = blockIdx.x * 16 + wave * 4;
  const ushort* Qh = Qb + (size_t)bh * Tc * Dc;
  const ushort* Kth = Ktb + (size_t)bh * Dc * Tc;
  const ushort* Vh = Vb + (size_t)bh * Tc * Dc;
  float q[4], m[4], l[4], o[4];
  #pragma unroll
  for (int i = 0; i < 4; ++i) {
    q[i] = bf2f(Qh[(size_t)(r0 + i) * Dc + lane]) * 0.125f;  // 1/sqrt(64)
    m[i] = -INFINITY; l[i] = 0.f; o[i] = 0.f;
  }
  const int kmax = r0 + 3;
  for (int kc = 0; kc <= kmax; kc += 64) {
    float s[4] = {0.f, 0.f, 0.f, 0.f};
    const ushort* kp = Kth + kc + lane;
    #pragma unroll
    for (int d = 0; d < 64; ++d) {
      float kv = bf2f(kp[(size_t)d * Tc]);
      s[0] += __shfl(q[0], d) * kv;
      s[1] += __shfl(q[1], d) * kv;
      s[2] += __shfl(q[2], d) * kv;
      s[3] += __shfl(q[3], d) * kv;
    }
    const int kpos = kc + lane;
    float p[4];
    #pragma unroll
    for (int i = 0; i < 4; ++i) {
      float si = (kpos <= r0 + i) ? s[i] : -INFINITY;
      float cm = wmax(si);
      float mn = fmaxf(m[i], cm);          // finite after first chunk
      float sc = __expf(m[i] - mn);        // 0 on first chunk, no NaN
      p[i] = __expf(si - mn);              // 0 for masked lanes
      l[i] = l[i] * sc + wsum(p[i]);
      o[i] *= sc;
      m[i] = mn;
    }
    const ushort* vp = Vh + (size_t)kc * Dc + lane;
    #pragma unroll
    for (int k = 0; k < 64; ++k) {
      float vv = bf2f(vp[(size_t)k * Dc]);
      o[0] += __shfl(p[0], k) * vv;
      o[1] += __shfl(p[1], k) * vv;
      o[2] += __shfl(p[2], k) * vv;
      o[3] += __shfl(p[3], k) * vv;
    }
  }
  const int b = bh >> 4, h = bh & 15;
  #pragma unroll
  for (int i = 0; i < 4; ++i) {
    size_t row = (size_t)b * Tc + (r0 + i);
    Yb[row * Cdim + h * Dc + lane] = f2bf(o[i] / l[i]);
  }
}

// ---------- GEMM 2: out = y @ W_out + b_out ----------
__global__ __launch_bounds__(256) void gemm_out(const ushort* __restrict__ A,
                                                const ushort* __restrict__ Bt,
                                                const ushort* __restrict__ bias,
                                                void* __restrict__ out,
                                                const int* __restrict__ flag) {
  constexpr int K = 1024;
  __shared__ __align__(16) ushort As[64 * 40];
  __shared__ __align__(16) ushort Bs[64 * 40];
  const int tid = threadIdx.x;
  const int wave = tid >> 6, lane = tid & 63;
  const int m0 = blockIdx.y * 64;
  const int n0 = blockIdx.x * 64;
  const int srow = tid >> 2;
  const int scol = (tid & 3) * 8;
  const size_t a_src = (size_t)(m0 + srow) * K + scol;
  const size_t b_src = (size_t)(n0 + srow) * K + scol;
  const int lds_dst = srow * 40 + scol;
  const int mr = lane & 15, quad = lane >> 4;
  const int a_off = (wave * 16 + mr) * 40 + quad * 8;
  floatx4 acc[4] = {{0.f,0.f,0.f,0.f},{0.f,0.f,0.f,0.f},{0.f,0.f,0.f,0.f},{0.f,0.f,0.f,0.f}};
  for (int k0 = 0; k0 < K; k0 += 32) {
    uint4 av = *(const uint4*)(A + a_src + k0);
    uint4 bv = *(const uint4*)(Bt + b_src + k0);
    __syncthreads();
    *(uint4*)(As + lds_dst) = av;
    *(uint4*)(Bs + lds_dst) = bv;
    __syncthreads();
    bf16x8 af = *(const bf16x8*)(As + a_off);
    #pragma unroll
    for (int c = 0; c < 4; ++c) {
      bf16x8 bf = *(const bf16x8*)(Bs + (c * 16 + mr) * 40 + quad * 8);
      acc[c] = __builtin_amdgcn_mfma_f32_16x16x32_bf16(af, bf, acc[c], 0, 0, 0);
    }
  }
  const bool isbf = (*flag != 0);
  #pragma unroll
  for (int c = 0; c < 4; ++c) {
    const int col = n0 + c * 16 + mr;
    const float bi = bf2f(bias[col]);
    #pragma unroll
    for (int r = 0; r < 4; ++r) {
      const int row = m0 + wave * 16 + quad * 4 + r;
      const float v = acc[c][r] + bi;
      const size_t idx = (size_t)row * 1024 + col;
      if (isbf) ((ushort*)out)[idx] = f2bf(v);
      else      ((float*)out)[idx] = v;
    }
  }
}

extern "C" void kernel_launch(void* const* d_in, const int* in_sizes, int n_in,
                              void* d_out, int out_size, void* d_ws, size_t ws_size,
                              hipStream_t stream) {
  const void* x    = d_in[0];
  const void* Wqkv = d_in[1];
  const void* bqkv = d_in[2];
  const void* Wout = d_in[3];
  const void* bout = d_in[4];

  char* ws = (char*)d_ws;
  size_t off = 0;
  auto alloc = [&](size_t bytes) { size_t r = off; off += (bytes + 255) & ~(size_t)255; return r; };

  int*    flag = (int*)   (ws + alloc(256));
  ushort* xb   = (ushort*)(ws + alloc((size_t)Mrows * Cdim * 2));      // also reused as Y
  ushort* wqt  = (ushort*)(ws + alloc((size_t)3 * Cdim * Cdim * 2));
  ushort* wot  = (ushort*)(ws + alloc((size_t)Cdim * Cdim * 2));
  ushort* bqb  = (ushort*)(ws + alloc((size_t)3 * Cdim * 2));
  ushort* bob  = (ushort*)(ws + alloc((size_t)Cdim * 2));
  ushort* Qb   = (ushort*)(ws + alloc((size_t)Mrows * Cdim * 2));
  ushort* Ktb  = (ushort*)(ws + alloc((size_t)Mrows * Cdim * 2));
  ushort* Vb   = (ushort*)(ws + alloc((size_t)Mrows * Cdim * 2));
  ushort* Yb   = xb;  // x is dead after gemm_qkv; reuse to keep ws footprint ~76 MB

  sniff_kernel<<<1, 256, 0, stream>>>((const unsigned int*)x, flag);

  convert_vec<<<(Mrows * Cdim) / 1024, 256, 0, stream>>>(x, xb, (size_t)Mrows * Cdim, flag);
  convert_vec<<<3, 256, 0, stream>>>(bqkv, bqb, 3 * Cdim, flag);
  convert_vec<<<1, 256, 0, stream>>>(bout, bob, Cdim, flag);
  transpose_convert<<<dim3(96, 32), dim3(32, 8), 0, stream>>>(Wqkv, wqt, Cdim, 3 * Cdim, flag);
  transpose_convert<<<dim3(32, 32), dim3(32, 8), 0, stream>>>(Wout, wot, Cdim, Cdim, flag);

  gemm_qkv<<<dim3(48, 128), 256, 0, stream>>>(xb, wqt, bqb, Qb, Ktb, Vb);
  attn_kernel<<<dim3(Tc / 16, 64), 256, 0, stream>>>(Qb, Ktb, Vb, Yb);
  gemm_out<<<dim3(16, 128), 256, 0, stream>>>(Yb, wot, bob, d_out, flag);
}

// Round 2
// 725.403 us; speedup vs baseline: 6.1663x; 6.1663x over previous
//
#include <hip/hip_runtime.h>
#include <math.h>

typedef __bf16 bf16x8 __attribute__((ext_vector_type(8)));
typedef float floatx4 __attribute__((ext_vector_type(4)));

#define Tc 2048
#define Cdim 1024
#define Hc 16
#define Dc 64
#define Mrows 8192

__device__ __forceinline__ float bf2f(ushort u) {
  union { float f; unsigned int i; } v; v.i = ((unsigned int)u) << 16; return v.f;
}
__device__ __forceinline__ ushort f2bf(float f) {
  union { float f; unsigned int i; } v; v.f = f;
  unsigned int r = (v.i + 0x7FFFu + ((v.i >> 16) & 1u)) >> 16;
  return (ushort)r;
}

// ---------- dtype sniff: 1 = bf16-packed input, 0 = fp32 input ----------
__global__ void sniff_kernel(const unsigned int* __restrict__ x, int* __restrict__ flag) {
  __shared__ int cnt;
  if (threadIdx.x == 0) cnt = 0;
  __syncthreads();
  int local = 0;
  for (int i = threadIdx.x; i < 1024; i += 256) {
    unsigned int w = x[i];
    unsigned int e = (w >> 7) & 0xFFu;  // exponent field of LOW bf16 half
    if (e >= 100u && e <= 140u) local++;
  }
  atomicAdd(&cnt, local);
  __syncthreads();
  if (threadIdx.x == 0) *flag = (cnt >= 614) ? 1 : 0;
}

// ---------- convert (copy) to canonical bf16 bits ----------
__global__ void convert_vec(const void* __restrict__ src, ushort* __restrict__ dst,
                            size_t n, const int* __restrict__ flag) {
  size_t i = (size_t)blockIdx.x * blockDim.x + threadIdx.x;
  size_t base = i * 4;
  if (base >= n) return;
  if (*flag) {
    *(ushort4*)(dst + base) = ((const ushort4*)src)[i];
  } else {
    float4 f = ((const float4*)src)[i];
    dst[base + 0] = f2bf(f.x);
    dst[base + 1] = f2bf(f.y);
    dst[base + 2] = f2bf(f.z);
    dst[base + 3] = f2bf(f.w);
  }
}

// ---------- transpose + convert: src[R][Ccols] -> dst[Ccols][R] (bf16) ----------
__global__ void transpose_convert(const void* __restrict__ src, ushort* __restrict__ dst,
                                  int R, int Ccols, const int* __restrict__ flag) {
  __shared__ float tile[32][33];
  const int bx = blockIdx.x, by = blockIdx.y;
  const int tx = threadIdx.x, ty = threadIdx.y;
  const bool isbf = (*flag != 0);
  #pragma unroll
  for (int i = ty; i < 32; i += 8) {
    int r = by * 32 + i;
    int c = bx * 32 + tx;
    float v = isbf ? bf2f(((const ushort*)src)[(size_t)r * Ccols + c])
                   : ((const float*)src)[(size_t)r * Ccols + c];
    tile[i][tx] = v;
  }
  __syncthreads();
  #pragma unroll
  for (int i = ty; i < 32; i += 8) {
    int cc = bx * 32 + i;       // new row (old col)
    int rr = by * 32 + tx;      // new col (old row)
    dst[(size_t)cc * R + rr] = f2bf(tile[tx][i]);
  }
}

// ---------- GEMM 1: qkv = x @ W_qkv + b, scatter into Q / K / V^T ----------
// A[M,K] bf16, Bt[N,K] bf16. 64x64 tile, BK=32, 4 waves, mfma 16x16x32.
// Q: [bh][t][d]   K: [bh][t][d]   V^T: [bh][d][t]  (MFMA-attention-ready)
__global__ __launch_bounds__(256) void gemm_qkv(const ushort* __restrict__ A,
                                                const ushort* __restrict__ Bt,
                                                const ushort* __restrict__ bias,
                                                ushort* __restrict__ Qb,
                                                ushort* __restrict__ Kb,
                                                ushort* __restrict__ Vtb) {
  constexpr int K = 1024;
  __shared__ __align__(16) ushort As[64 * 40];
  __shared__ __align__(16) ushort Bs[64 * 40];
  const int tid = threadIdx.x;
  const int wave = tid >> 6, lane = tid & 63;
  const int m0 = blockIdx.y * 64;
  const int n0 = blockIdx.x * 64;
  const int srow = tid >> 2;          // 0..63
  const int scol = (tid & 3) * 8;     // 0,8,16,24
  const size_t a_src = (size_t)(m0 + srow) * K + scol;
  const size_t b_src = (size_t)(n0 + srow) * K + scol;
  const int lds_dst = srow * 40 + scol;
  const int mr = lane & 15, quad = lane >> 4;
  const int a_off = (wave * 16 + mr) * 40 + quad * 8;
  floatx4 acc[4] = {{0.f,0.f,0.f,0.f},{0.f,0.f,0.f,0.f},{0.f,0.f,0.f,0.f},{0.f,0.f,0.f,0.f}};
  for (int k0 = 0; k0 < K; k0 += 32) {
    uint4 av = *(const uint4*)(A + a_src + k0);
    uint4 bv = *(const uint4*)(Bt + b_src + k0);
    __syncthreads();
    *(uint4*)(As + lds_dst) = av;
    *(uint4*)(Bs + lds_dst) = bv;
    __syncthreads();
    bf16x8 af = *(const bf16x8*)(As + a_off);
    #pragma unroll
    for (int c = 0; c < 4; ++c) {
      bf16x8 bf = *(const bf16x8*)(Bs + (c * 16 + mr) * 40 + quad * 8);
      acc[c] = __builtin_amdgcn_mfma_f32_16x16x32_bf16(af, bf, acc[c], 0, 0, 0);
    }
  }
  // epilogue: D mapping col=lane&15 (within 16-tile), row=quad*4+reg
  #pragma unroll
  for (int c = 0; c < 4; ++c) {
    const int col = n0 + c * 16 + mr;        // 0..3071
    const float bi = bf2f(bias[col]);
    const int which = col >> 10;             // 0=Q 1=K 2=V
    const int within = col & 1023;
    const int h = within >> 6, d = within & 63;
    #pragma unroll
    for (int r = 0; r < 4; ++r) {
      const int row = m0 + wave * 16 + quad * 4 + r;   // 0..8191
      const float v = acc[c][r] + bi;
      const int b = row >> 11, t = row & 2047;
      const size_t hb = (size_t)(b * Hc + h);
      const ushort ub = f2bf(v);
      if (which == 0)      Qb[(hb * Tc + t) * Dc + d] = ub;
      else if (which == 1) Kb[(hb * Tc + t) * Dc + d] = ub;
      else                 Vtb[(hb * Dc + d) * Tc + t] = ub;
    }
  }
}

// ---------- MFMA flash attention ----------
// grid: (T/64, B*H), 4 waves/block, each wave owns 16 q-rows independently
// (no __syncthreads; per-wave private LDS, parity double-buffered).
// S frags: C-layout row=quad*4+reg (q), col=lane&15 (kcol). P->LDS->A-layout.
__global__ __launch_bounds__(256) void attn_mfma(const ushort* __restrict__ Qb,
                                                 const ushort* __restrict__ Kb,
                                                 const ushort* __restrict__ Vtb,
                                                 ushort* __restrict__ Yb) {
  constexpr int PLD = 72;  // 64 + 8 pad: A-frag b128 reads land 2-way (free)
  __shared__ __align__(16) ushort Plds[2][4][16 * PLD];
  const int bh = blockIdx.y;
  const int wave = threadIdx.x >> 6, lane = threadIdx.x & 63;
  const int col = lane & 15, quad = lane >> 4;
  const int q0w = blockIdx.x * 64 + wave * 16;
  const ushort* Qh = Qb + (size_t)bh * Tc * Dc;
  const ushort* Kh = Kb + (size_t)bh * Tc * Dc;
  const ushort* Vth = Vtb + (size_t)bh * Dc * Tc;

  bf16x8 qa0 = *(const bf16x8*)(Qh + (size_t)(q0w + col) * Dc + quad * 8);
  bf16x8 qa1 = *(const bf16x8*)(Qh + (size_t)(q0w + col) * Dc + 32 + quad * 8);

  floatx4 o[4] = {{0.f,0.f,0.f,0.f},{0.f,0.f,0.f,0.f},{0.f,0.f,0.f,0.f},{0.f,0.f,0.f,0.f}};
  float m4[4] = {-INFINITY, -INFINITY, -INFINITY, -INFINITY};
  float l4[4] = {0.f, 0.f, 0.f, 0.f};

  const int kend = q0w + 15;   // last valid key for this wave's q-tile
  int parity = 0;
  for (int kc = 0; kc <= kend; kc += 64, parity ^= 1) {
    // ---- S = Q K^T (scaled later) ----
    floatx4 sf[4] = {{0.f,0.f,0.f,0.f},{0.f,0.f,0.f,0.f},{0.f,0.f,0.f,0.f},{0.f,0.f,0.f,0.f}};
    #pragma unroll
    for (int ct = 0; ct < 4; ++ct) {
      const ushort* kp = Kh + (size_t)(kc + ct * 16 + col) * Dc + quad * 8;
      bf16x8 kb0 = *(const bf16x8*)(kp);
      bf16x8 kb1 = *(const bf16x8*)(kp + 32);
      sf[ct] = __builtin_amdgcn_mfma_f32_16x16x32_bf16(qa0, kb0, sf[ct], 0, 0, 0);
      sf[ct] = __builtin_amdgcn_mfma_f32_16x16x32_bf16(qa1, kb1, sf[ct], 0, 0, 0);
    }
    // ---- online softmax on C-layout (per lane: 4 q-rows x 4 col-tiles) ----
    ushort* Pw = Plds[parity][wave];
    #pragma unroll
    for (int r = 0; r < 4; ++r) {
      const int q = q0w + quad * 4 + r;
      float sv[4];
      float mx = -INFINITY;
      #pragma unroll
      for (int ct = 0; ct < 4; ++ct) {
        const int kcol = kc + ct * 16 + col;
        float s = sf[ct][r] * 0.125f;          // 1/sqrt(64)
        s = (kcol <= q) ? s : -INFINITY;
        sv[ct] = s;
        mx = fmaxf(mx, s);
      }
      // row-max across the 16-lane quad-group (offsets stay inside group)
      mx = fmaxf(mx, __shfl_xor(mx, 1));
      mx = fmaxf(mx, __shfl_xor(mx, 2));
      mx = fmaxf(mx, __shfl_xor(mx, 4));
      mx = fmaxf(mx, __shfl_xor(mx, 8));
      const float mn = fmaxf(m4[r], mx);       // always finite (kc <= q0w <= q)
      const float alpha = __expf(m4[r] - mn);
      m4[r] = mn;
      float ps = 0.f;
      #pragma unroll
      for (int ct = 0; ct < 4; ++ct) {
        float p = __expf(sv[ct] - mn);         // masked lanes -> exp(-inf)=0
        ps += p;
        Pw[(quad * 4 + r) * PLD + ct * 16 + col] = f2bf(p);
      }
      ps += __shfl_xor(ps, 1);
      ps += __shfl_xor(ps, 2);
      ps += __shfl_xor(ps, 4);
      ps += __shfl_xor(ps, 8);
      l4[r] = l4[r] * alpha + ps;
      #pragma unroll
      for (int dt = 0; dt < 4; ++dt) o[dt][r] *= alpha;
    }
    // ---- P (A-layout via LDS) x V^T ----
    bf16x8 pa0 = *(const bf16x8*)(Pw + col * PLD + quad * 8);
    bf16x8 pa1 = *(const bf16x8*)(Pw + col * PLD + 32 + quad * 8);
    #pragma unroll
    for (int dt = 0; dt < 4; ++dt) {
      const ushort* vp = Vth + (size_t)(dt * 16 + col) * Tc + kc + quad * 8;
      bf16x8 vb0 = *(const bf16x8*)(vp);
      bf16x8 vb1 = *(const bf16x8*)(vp + 32);
      o[dt] = __builtin_amdgcn_mfma_f32_16x16x32_bf16(pa0, vb0, o[dt], 0, 0, 0);
      o[dt] = __builtin_amdgcn_mfma_f32_16x16x32_bf16(pa1, vb1, o[dt], 0, 0, 0);
    }
  }
  // ---- normalize + write Y[B,T,C] ----
  const int b = bh >> 4, h = bh & 15;
  #pragma unroll
  for (int r = 0; r < 4; ++r) {
    const int q = q0w + quad * 4 + r;
    const float inv = 1.f / l4[r];
    const size_t base = ((size_t)b * Tc + q) * Cdim + h * Dc;
    #pragma unroll
    for (int dt = 0; dt < 4; ++dt)
      Yb[base + dt * 16 + col] = f2bf(o[dt][r] * inv);
  }
}

// ---------- GEMM 2: out = y @ W_out + b_out ----------
__global__ __launch_bounds__(256) void gemm_out(const ushort* __restrict__ A,
                                                const ushort* __restrict__ Bt,
                                                const ushort* __restrict__ bias,
                                                void* __restrict__ out,
                                                const int* __restrict__ flag) {
  constexpr int K = 1024;
  __shared__ __align__(16) ushort As[64 * 40];
  __shared__ __align__(16) ushort Bs[64 * 40];
  const int tid = threadIdx.x;
  const int wave = tid >> 6, lane = tid & 63;
  const int m0 = blockIdx.y * 64;
  const int n0 = blockIdx.x * 64;
  const int srow = tid >> 2;
  const int scol = (tid & 3) * 8;
  const size_t a_src = (size_t)(m0 + srow) * K + scol;
  const size_t b_src = (size_t)(n0 + srow) * K + scol;
  const int lds_dst = srow * 40 + scol;
  const int mr = lane & 15, quad = lane >> 4;
  const int a_off = (wave * 16 + mr) * 40 + quad * 8;
  floatx4 acc[4] = {{0.f,0.f,0.f,0.f},{0.f,0.f,0.f,0.f},{0.f,0.f,0.f,0.f},{0.f,0.f,0.f,0.f}};
  for (int k0 = 0; k0 < K; k0 += 32) {
    uint4 av = *(const uint4*)(A + a_src + k0);
    uint4 bv = *(const uint4*)(Bt + b_src + k0);
    __syncthreads();
    *(uint4*)(As + lds_dst) = av;
    *(uint4*)(Bs + lds_dst) = bv;
    __syncthreads();
    bf16x8 af = *(const bf16x8*)(As + a_off);
    #pragma unroll
    for (int c = 0; c < 4; ++c) {
      bf16x8 bf = *(const bf16x8*)(Bs + (c * 16 + mr) * 40 + quad * 8);
      acc[c] = __builtin_amdgcn_mfma_f32_16x16x32_bf16(af, bf, acc[c], 0, 0, 0);
    }
  }
  const bool isbf = (*flag != 0);
  #pragma unroll
  for (int c = 0; c < 4; ++c) {
    const int col = n0 + c * 16 + mr;
    const float bi = bf2f(bias[col]);
    #pragma unroll
    for (int r = 0; r < 4; ++r) {
      const int row = m0 + wave * 16 + quad * 4 + r;
      const float v = acc[c][r] + bi;
      const size_t idx = (size_t)row * 1024 + col;
      if (isbf) ((ushort*)out)[idx] = f2bf(v);
      else      ((float*)out)[idx] = v;
    }
  }
}

extern "C" void kernel_launch(void* const* d_in, const int* in_sizes, int n_in,
                              void* d_out, int out_size, void* d_ws, size_t ws_size,
                              hipStream_t stream) {
  const void* x    = d_in[0];
  const void* Wqkv = d_in[1];
  const void* bqkv = d_in[2];
  const void* Wout = d_in[3];
  const void* bout = d_in[4];

  char* ws = (char*)d_ws;
  size_t off = 0;
  auto alloc = [&](size_t bytes) { size_t r = off; off += (bytes + 255) & ~(size_t)255; return r; };

  int*    flag = (int*)   (ws + alloc(256));
  ushort* xb   = (ushort*)(ws + alloc((size_t)Mrows * Cdim * 2));      // also reused as Y
  ushort* wqt  = (ushort*)(ws + alloc((size_t)3 * Cdim * Cdim * 2));
  ushort* wot  = (ushort*)(ws + alloc((size_t)Cdim * Cdim * 2));
  ushort* bqb  = (ushort*)(ws + alloc((size_t)3 * Cdim * 2));
  ushort* bob  = (ushort*)(ws + alloc((size_t)Cdim * 2));
  ushort* Qb   = (ushort*)(ws + alloc((size_t)Mrows * Cdim * 2));
  ushort* Kb   = (ushort*)(ws + alloc((size_t)Mrows * Cdim * 2));
  ushort* Vtb  = (ushort*)(ws + alloc((size_t)Mrows * Cdim * 2));
  ushort* Yb   = xb;  // x is dead after gemm_qkv; reuse to keep ws footprint ~76 MB

  sniff_kernel<<<1, 256, 0, stream>>>((const unsigned int*)x, flag);

  convert_vec<<<(Mrows * Cdim) / 1024, 256, 0, stream>>>(x, xb, (size_t)Mrows * Cdim, flag);
  convert_vec<<<3, 256, 0, stream>>>(bqkv, bqb, 3 * Cdim, flag);
  convert_vec<<<1, 256, 0, stream>>>(bout, bob, Cdim, flag);
  transpose_convert<<<dim3(96, 32), dim3(32, 8), 0, stream>>>(Wqkv, wqt, Cdim, 3 * Cdim, flag);
  transpose_convert<<<dim3(32, 32), dim3(32, 8), 0, stream>>>(Wout, wot, Cdim, Cdim, flag);

  gemm_qkv<<<dim3(48, 128), 256, 0, stream>>>(xb, wqt, bqb, Qb, Kb, Vtb);
  attn_mfma<<<dim3(Tc / 64, 64), 256, 0, stream>>>(Qb, Kb, Vtb, Yb);
  gemm_out<<<dim3(16, 128), 256, 0, stream>>>(Yb, wot, bob, d_out, flag);
}

// Round 3
// 506.418 us; speedup vs baseline: 8.8328x; 1.4324x over previous
//
#include <hip/hip_runtime.h>
#include <math.h>

typedef __bf16 bf16x8 __attribute__((ext_vector_type(8)));
typedef float floatx4 __attribute__((ext_vector_type(4)));

#define Tc 2048
#define Cdim 1024
#define Hc 16
#define Dc 64
#define Mrows 8192

__device__ __forceinline__ float bf2f(ushort u) {
  union { float f; unsigned int i; } v; v.i = ((unsigned int)u) << 16; return v.f;
}
__device__ __forceinline__ ushort f2bf(float f) {
  union { float f; unsigned int i; } v; v.f = f;
  unsigned int r = (v.i + 0x7FFFu + ((v.i >> 16) & 1u)) >> 16;
  return (ushort)r;
}

// ---------- dtype sniff: 1 = bf16-packed input, 0 = fp32 input ----------
__global__ void sniff_kernel(const unsigned int* __restrict__ x, int* __restrict__ flag) {
  __shared__ int cnt;
  if (threadIdx.x == 0) cnt = 0;
  __syncthreads();
  int local = 0;
  for (int i = threadIdx.x; i < 1024; i += 256) {
    unsigned int w = x[i];
    unsigned int e = (w >> 7) & 0xFFu;  // exponent field of LOW bf16 half
    if (e >= 100u && e <= 140u) local++;
  }
  atomicAdd(&cnt, local);
  __syncthreads();
  if (threadIdx.x == 0) *flag = (cnt >= 614) ? 1 : 0;
}

// ---------- convert (copy) to canonical bf16 bits ----------
__global__ void convert_vec(const void* __restrict__ src, ushort* __restrict__ dst,
                            size_t n, const int* __restrict__ flag) {
  size_t i = (size_t)blockIdx.x * blockDim.x + threadIdx.x;
  size_t base = i * 4;
  if (base >= n) return;
  if (*flag) {
    *(ushort4*)(dst + base) = ((const ushort4*)src)[i];
  } else {
    float4 f = ((const float4*)src)[i];
    dst[base + 0] = f2bf(f.x);
    dst[base + 1] = f2bf(f.y);
    dst[base + 2] = f2bf(f.z);
    dst[base + 3] = f2bf(f.w);
  }
}

// ---------- transpose + convert: src[R][Ccols] -> dst[Ccols][R] (bf16) ----------
__global__ void transpose_convert(const void* __restrict__ src, ushort* __restrict__ dst,
                                  int R, int Ccols, const int* __restrict__ flag) {
  __shared__ float tile[32][33];
  const int bx = blockIdx.x, by = blockIdx.y;
  const int tx = threadIdx.x, ty = threadIdx.y;
  const bool isbf = (*flag != 0);
  #pragma unroll
  for (int i = ty; i < 32; i += 8) {
    int r = by * 32 + i;
    int c = bx * 32 + tx;
    float v = isbf ? bf2f(((const ushort*)src)[(size_t)r * Ccols + c])
                   : ((const float*)src)[(size_t)r * Ccols + c];
    tile[i][tx] = v;
  }
  __syncthreads();
  #pragma unroll
  for (int i = ty; i < 32; i += 8) {
    int cc = bx * 32 + i;       // new row (old col)
    int rr = by * 32 + tx;      // new col (old row)
    dst[(size_t)cc * R + rr] = f2bf(tile[tx][i]);
  }
}

// ---------- GEMM 1: qkv = x @ W_qkv + b, scatter into Q / K / V^T ----------
__global__ __launch_bounds__(256) void gemm_qkv(const ushort* __restrict__ A,
                                                const ushort* __restrict__ Bt,
                                                const ushort* __restrict__ bias,
                                                ushort* __restrict__ Qb,
                                                ushort* __restrict__ Kb,
                                                ushort* __restrict__ Vtb) {
  constexpr int K = 1024;
  __shared__ __align__(16) ushort As[64 * 40];
  __shared__ __align__(16) ushort Bs[64 * 40];
  const int tid = threadIdx.x;
  const int wave = tid >> 6, lane = tid & 63;
  const int m0 = blockIdx.y * 64;
  const int n0 = blockIdx.x * 64;
  const int srow = tid >> 2;          // 0..63
  const int scol = (tid & 3) * 8;     // 0,8,16,24
  const size_t a_src = (size_t)(m0 + srow) * K + scol;
  const size_t b_src = (size_t)(n0 + srow) * K + scol;
  const int lds_dst = srow * 40 + scol;
  const int mr = lane & 15, quad = lane >> 4;
  const int a_off = (wave * 16 + mr) * 40 + quad * 8;
  floatx4 acc[4] = {{0.f,0.f,0.f,0.f},{0.f,0.f,0.f,0.f},{0.f,0.f,0.f,0.f},{0.f,0.f,0.f,0.f}};
  for (int k0 = 0; k0 < K; k0 += 32) {
    uint4 av = *(const uint4*)(A + a_src + k0);
    uint4 bv = *(const uint4*)(Bt + b_src + k0);
    __syncthreads();
    *(uint4*)(As + lds_dst) = av;
    *(uint4*)(Bs + lds_dst) = bv;
    __syncthreads();
    bf16x8 af = *(const bf16x8*)(As + a_off);
    #pragma unroll
    for (int c = 0; c < 4; ++c) {
      bf16x8 bf = *(const bf16x8*)(Bs + (c * 16 + mr) * 40 + quad * 8);
      acc[c] = __builtin_amdgcn_mfma_f32_16x16x32_bf16(af, bf, acc[c], 0, 0, 0);
    }
  }
  #pragma unroll
  for (int c = 0; c < 4; ++c) {
    const int col = n0 + c * 16 + mr;        // 0..3071
    const float bi = bf2f(bias[col]);
    const int which = col >> 10;             // 0=Q 1=K 2=V
    const int within = col & 1023;
    const int h = within >> 6, d = within & 63;
    #pragma unroll
    for (int r = 0; r < 4; ++r) {
      const int row = m0 + wave * 16 + quad * 4 + r;   // 0..8191
      const float v = acc[c][r] + bi;
      const int b = row >> 11, t = row & 2047;
      const size_t hb = (size_t)(b * Hc + h);
      const ushort ub = f2bf(v);
      if (which == 0)      Qb[(hb * Tc + t) * Dc + d] = ub;
      else if (which == 1) Kb[(hb * Tc + t) * Dc + d] = ub;
      else                 Vtb[(hb * Dc + d) * Tc + t] = ub;
    }
  }
}

// ---------- MFMA flash attention v2 ----------
// grid: (T/128 = 16 panels, B*H). 4 waves/block, each wave owns 32 q-rows
// (2 m-frags), independent (no barriers; per-wave parity-dbuf LDS for P).
// Longest-first: panel = gridDim.x-1-blockIdx.x kills the causal-triangle tail.
// P LDS is XOR-swizzled (8-elem groups, g^=((row>>2)<<1)) -> conflict-free
// b16 writes, 16B-aligned b128 A-frag reads.
__global__ __launch_bounds__(256, 2) void attn_mfma(const ushort* __restrict__ Qb,
                                                    const ushort* __restrict__ Kb,
                                                    const ushort* __restrict__ Vtb,
                                                    ushort* __restrict__ Yb) {
  __shared__ __align__(16) ushort Plds[2][4][2048];  // [parity][wave][mf*1024 + row*64 + swz]
  const int bh = blockIdx.y;
  const int wave = threadIdx.x >> 6, lane = threadIdx.x & 63;
  const int col = lane & 15, quad = lane >> 4;
  const int panel = gridDim.x - 1 - blockIdx.x;      // longest job first
  const int q0w = panel * 128 + wave * 32;
  const ushort* Qh = Qb + (size_t)bh * Tc * Dc;
  const ushort* Kh = Kb + (size_t)bh * Tc * Dc;
  const ushort* Vth = Vtb + (size_t)bh * Dc * Tc;

  bf16x8 qa[2][2];
  #pragma unroll
  for (int mf = 0; mf < 2; ++mf) {
    const ushort* qp = Qh + (size_t)(q0w + mf * 16 + col) * Dc + quad * 8;
    qa[mf][0] = *(const bf16x8*)(qp);
    qa[mf][1] = *(const bf16x8*)(qp + 32);
  }

  floatx4 o[2][4];
  float m4[2][4], l4[2][4];
  #pragma unroll
  for (int mf = 0; mf < 2; ++mf)
    #pragma unroll
    for (int i = 0; i < 4; ++i) {
      o[mf][i] = (floatx4){0.f, 0.f, 0.f, 0.f};
      m4[mf][i] = -INFINITY; l4[mf][i] = 0.f;
    }

  const int kend = q0w + 31;
  int parity = 0;
  for (int kc = 0; kc <= kend; kc += 64, parity ^= 1) {
    // ---- S = Q K^T : 2 m-frags share each K b-frag ----
    floatx4 sf[2][4];
    #pragma unroll
    for (int mf = 0; mf < 2; ++mf)
      #pragma unroll
      for (int ct = 0; ct < 4; ++ct) sf[mf][ct] = (floatx4){0.f, 0.f, 0.f, 0.f};
    #pragma unroll
    for (int ct = 0; ct < 4; ++ct) {
      const ushort* kp = Kh + (size_t)(kc + ct * 16 + col) * Dc + quad * 8;
      bf16x8 kb0 = *(const bf16x8*)(kp);
      bf16x8 kb1 = *(const bf16x8*)(kp + 32);
      sf[0][ct] = __builtin_amdgcn_mfma_f32_16x16x32_bf16(qa[0][0], kb0, sf[0][ct], 0, 0, 0);
      sf[0][ct] = __builtin_amdgcn_mfma_f32_16x16x32_bf16(qa[0][1], kb1, sf[0][ct], 0, 0, 0);
      sf[1][ct] = __builtin_amdgcn_mfma_f32_16x16x32_bf16(qa[1][0], kb0, sf[1][ct], 0, 0, 0);
      sf[1][ct] = __builtin_amdgcn_mfma_f32_16x16x32_bf16(qa[1][1], kb1, sf[1][ct], 0, 0, 0);
    }
    // ---- V prefetch: issue now, consume after softmax ----
    bf16x8 vb[4][2];
    #pragma unroll
    for (int dt = 0; dt < 4; ++dt) {
      const ushort* vp = Vth + (size_t)(dt * 16 + col) * Tc + kc + quad * 8;
      vb[dt][0] = *(const bf16x8*)(vp);
      vb[dt][1] = *(const bf16x8*)(vp + 32);
    }
    // ---- online softmax (C-layout) + swizzled P writes ----
    ushort* Pw = Plds[parity][wave];
    #pragma unroll
    for (int mf = 0; mf < 2; ++mf) {
      #pragma unroll
      for (int r = 0; r < 4; ++r) {
        const int q = q0w + mf * 16 + quad * 4 + r;
        float sv[4];
        float mx = -INFINITY;
        #pragma unroll
        for (int ct = 0; ct < 4; ++ct) {
          const int kcol = kc + ct * 16 + col;
          float s = sf[mf][ct][r] * 0.125f;    // 1/sqrt(64)
          s = (kcol <= q) ? s : -INFINITY;
          sv[ct] = s;
          mx = fmaxf(mx, s);
        }
        mx = fmaxf(mx, __shfl_xor(mx, 1));
        mx = fmaxf(mx, __shfl_xor(mx, 2));
        mx = fmaxf(mx, __shfl_xor(mx, 4));
        mx = fmaxf(mx, __shfl_xor(mx, 8));
        const float mn = fmaxf(m4[mf][r], mx);   // finite: chunk0 always has unmasked cols
        const float alpha = __expf(m4[mf][r] - mn);
        m4[mf][r] = mn;
        float ps = 0.f;
        const int row = quad * 4 + r;
        #pragma unroll
        for (int ct = 0; ct < 4; ++ct) {
          float p = __expf(sv[ct] - mn);         // masked -> 0
          ps += p;
          const int g = 2 * ct + (col >> 3);
          Pw[mf * 1024 + row * 64 + ((g ^ (quad << 1)) * 8) + (col & 7)] = f2bf(p);
        }
        ps += __shfl_xor(ps, 1);
        ps += __shfl_xor(ps, 2);
        ps += __shfl_xor(ps, 4);
        ps += __shfl_xor(ps, 8);
        l4[mf][r] = l4[mf][r] * alpha + ps;
        #pragma unroll
        for (int dt = 0; dt < 4; ++dt) o[mf][dt][r] *= alpha;
      }
    }
    // ---- P (A-layout, swizzled read) x V^T ----
    const int fsw = ((col >> 2) & 3) << 1;
    #pragma unroll
    for (int mf = 0; mf < 2; ++mf) {
      bf16x8 pa0 = *(const bf16x8*)(Pw + mf * 1024 + col * 64 + ((quad ^ fsw) * 8));
      bf16x8 pa1 = *(const bf16x8*)(Pw + mf * 1024 + col * 64 + (((4 + quad) ^ fsw) * 8));
      #pragma unroll
      for (int dt = 0; dt < 4; ++dt) {
        o[mf][dt] = __builtin_amdgcn_mfma_f32_16x16x32_bf16(pa0, vb[dt][0], o[mf][dt], 0, 0, 0);
        o[mf][dt] = __builtin_amdgcn_mfma_f32_16x16x32_bf16(pa1, vb[dt][1], o[mf][dt], 0, 0, 0);
      }
    }
  }
  // ---- normalize + write Y[B,T,C] ----
  const int b = bh >> 4, h = bh & 15;
  #pragma unroll
  for (int mf = 0; mf < 2; ++mf) {
    #pragma unroll
    for (int r = 0; r < 4; ++r) {
      const int q = q0w + mf * 16 + quad * 4 + r;
      const float inv = 1.f / l4[mf][r];
      const size_t base = ((size_t)b * Tc + q) * Cdim + h * Dc;
      #pragma unroll
      for (int dt = 0; dt < 4; ++dt)
        Yb[base + dt * 16 + col] = f2bf(o[mf][dt][r] * inv);
    }
  }
}

// ---------- GEMM 2: out = y @ W_out + b_out ----------
__global__ __launch_bounds__(256) void gemm_out(const ushort* __restrict__ A,
                                                const ushort* __restrict__ Bt,
                                                const ushort* __restrict__ bias,
                                                void* __restrict__ out,
                                                const int* __restrict__ flag) {
  constexpr int K = 1024;
  __shared__ __align__(16) ushort As[64 * 40];
  __shared__ __align__(16) ushort Bs[64 * 40];
  const int tid = threadIdx.x;
  const int wave = tid >> 6, lane = tid & 63;
  const int m0 = blockIdx.y * 64;
  const int n0 = blockIdx.x * 64;
  const int srow = tid >> 2;
  const int scol = (tid & 3) * 8;
  const size_t a_src = (size_t)(m0 + srow) * K + scol;
  const size_t b_src = (size_t)(n0 + srow) * K + scol;
  const int lds_dst = srow * 40 + scol;
  const int mr = lane & 15, quad = lane >> 4;
  const int a_off = (wave * 16 + mr) * 40 + quad * 8;
  floatx4 acc[4] = {{0.f,0.f,0.f,0.f},{0.f,0.f,0.f,0.f},{0.f,0.f,0.f,0.f},{0.f,0.f,0.f,0.f}};
  for (int k0 = 0; k0 < K; k0 += 32) {
    uint4 av = *(const uint4*)(A + a_src + k0);
    uint4 bv = *(const uint4*)(Bt + b_src + k0);
    __syncthreads();
    *(uint4*)(As + lds_dst) = av;
    *(uint4*)(Bs + lds_dst) = bv;
    __syncthreads();
    bf16x8 af = *(const bf16x8*)(As + a_off);
    #pragma unroll
    for (int c = 0; c < 4; ++c) {
      bf16x8 bf = *(const bf16x8*)(Bs + (c * 16 + mr) * 40 + quad * 8);
      acc[c] = __builtin_amdgcn_mfma_f32_16x16x32_bf16(af, bf, acc[c], 0, 0, 0);
    }
  }
  const bool isbf = (*flag != 0);
  #pragma unroll
  for (int c = 0; c < 4; ++c) {
    const int col = n0 + c * 16 + mr;
    const float bi = bf2f(bias[col]);
    #pragma unroll
    for (int r = 0; r < 4; ++r) {
      const int row = m0 + wave * 16 + quad * 4 + r;
      const float v = acc[c][r] + bi;
      const size_t idx = (size_t)row * 1024 + col;
      if (isbf) ((ushort*)out)[idx] = f2bf(v);
      else      ((float*)out)[idx] = v;
    }
  }
}

extern "C" void kernel_launch(void* const* d_in, const int* in_sizes, int n_in,
                              void* d_out, int out_size, void* d_ws, size_t ws_size,
                              hipStream_t stream) {
  const void* x    = d_in[0];
  const void* Wqkv = d_in[1];
  const void* bqkv = d_in[2];
  const void* Wout = d_in[3];
  const void* bout = d_in[4];

  char* ws = (char*)d_ws;
  size_t off = 0;
  auto alloc = [&](size_t bytes) { size_t r = off; off += (bytes + 255) & ~(size_t)255; return r; };

  int*    flag = (int*)   (ws + alloc(256));
  ushort* xb   = (ushort*)(ws + alloc((size_t)Mrows * Cdim * 2));      // also reused as Y
  ushort* wqt  = (ushort*)(ws + alloc((size_t)3 * Cdim * Cdim * 2));
  ushort* wot  = (ushort*)(ws + alloc((size_t)Cdim * Cdim * 2));
  ushort* bqb  = (ushort*)(ws + alloc((size_t)3 * Cdim * 2));
  ushort* bob  = (ushort*)(ws + alloc((size_t)Cdim * 2));
  ushort* Qb   = (ushort*)(ws + alloc((size_t)Mrows * Cdim * 2));
  ushort* Kb   = (ushort*)(ws + alloc((size_t)Mrows * Cdim * 2));
  ushort* Vtb  = (ushort*)(ws + alloc((size_t)Mrows * Cdim * 2));
  ushort* Yb   = xb;  // x is dead after gemm_qkv; reuse to keep ws footprint ~76 MB

  sniff_kernel<<<1, 256, 0, stream>>>((const unsigned int*)x, flag);

  convert_vec<<<(Mrows * Cdim) / 1024, 256, 0, stream>>>(x, xb, (size_t)Mrows * Cdim, flag);
  convert_vec<<<3, 256, 0, stream>>>(bqkv, bqb, 3 * Cdim, flag);
  convert_vec<<<1, 256, 0, stream>>>(bout, bob, Cdim, flag);
  transpose_convert<<<dim3(96, 32), dim3(32, 8), 0, stream>>>(Wqkv, wqt, Cdim, 3 * Cdim, flag);
  transpose_convert<<<dim3(32, 32), dim3(32, 8), 0, stream>>>(Wout, wot, Cdim, Cdim, flag);

  gemm_qkv<<<dim3(48, 128), 256, 0, stream>>>(xb, wqt, bqb, Qb, Kb, Vtb);
  attn_mfma<<<dim3(Tc / 128, 64), 256, 0, stream>>>(Qb, Kb, Vtb, Yb);
  gemm_out<<<dim3(16, 128), 256, 0, stream>>>(Yb, wot, bob, d_out, flag);
}